// Round 1
// baseline (945.482 us; speedup 1.0000x reference)
//
#include <hip/hip_runtime.h>
#include <cstdint>
#include <cstddef>

#define NNODES 100000
#define NEDGES 1200000
#define KP1 4096
#define KP2 256
#define CAP_CAND 8192

typedef unsigned long long u64;
typedef unsigned int u32;

__device__ __forceinline__ float leakyf(float v){ return v >= 0.0f ? v : 0.01f*v; }

__device__ __forceinline__ u64 mono64(double d){
  u64 b = (u64)__double_as_longlong(d);
  return (b & 0x8000000000000000ull) ? ~b : (b | 0x8000000000000000ull);
}

// edge fetch supporting int32 or int64 storage (flag=1 -> int64)
__device__ __forceinline__ void get_edge(const int* eb, int flag, int e, int& s, int& d){
  if (flag){ s = eb[2*e]; d = eb[2*(NEDGES+e)]; }
  else     { s = eb[e];   d = eb[NEDGES+e]; }
}

// ---------------- setup: p-norms + edge dtype detect ----------------
__global__ void k_meta(const int* eb, const float* p1, const float* p2, int* meta, double* dscal){
  __shared__ double red[256];
  int t = threadIdx.x;
  double s1 = 0.0;
  if (t < 64){ double v = (double)p1[t]; s1 = v*v; }
  red[t] = s1; __syncthreads();
  for (int w = 128; w > 0; w >>= 1){ if (t < w) red[t] += red[t+w]; __syncthreads(); }
  if (t == 0) dscal[0] = 1.0 / sqrt(red[0]);
  __syncthreads();
  double v2 = (double)p2[t];
  red[t] = v2*v2; __syncthreads();
  for (int w = 128; w > 0; w >>= 1){ if (t < w) red[t] += red[t+w]; __syncthreads(); }
  if (t == 0){
    dscal[1] = 1.0 / sqrt(red[0]);
    int is64 = 1;
    for (int i = 1; i <= 127; i += 2) if (eb[i] != 0){ is64 = 0; break; }
    meta[0] = is64;
  }
}

// ---------------- GCN1 ----------------
__global__ void k_deg1(const int* eb, const int* meta, int* deg1){
  int e = blockIdx.x*256 + threadIdx.x;
  if (e >= NEDGES) return;
  int s, d; get_edge(eb, meta[0], e, s, d);
  (void)s;
  atomicAdd(&deg1[d], 1);
}

__global__ void k_dinv1(const int* deg1, float* dinv1){
  int n = blockIdx.x*256 + threadIdx.x;
  if (n >= NNODES) return;
  dinv1[n] = (float)(1.0 / sqrt((double)deg1[n] + 1.0));
}

__global__ void k_aggpos(const int* eb, const int* meta, const float* pos, const float* dinv1, float* aggpos){
  int e = blockIdx.x*256 + threadIdx.x;
  if (e >= NEDGES) return;
  int s, d; get_edge(eb, meta[0], e, s, d);
  float nrm = dinv1[s]*dinv1[d];
  atomicAdd(&aggpos[3*d+0], pos[3*s+0]*nrm);
  atomicAdd(&aggpos[3*d+1], pos[3*s+1]*nrm);
  atomicAdd(&aggpos[3*d+2], pos[3*s+2]*nrm);
}

// per-node: x1 row (in regs) -> score1 (f64) -> key + histogram
__global__ void k_score1(const float* pos, const float* aggpos, const float* dinv1,
                         const float* W1, const float* b1, const float* p1,
                         const double* dscal, float* score1, u64* key1, int* hist1){
  int n = blockIdx.x*256 + threadIdx.x;
  if (n >= NNODES) return;
  float di = dinv1[n], d2 = di*di;
  float t0 = aggpos[3*n+0] + pos[3*n+0]*d2;
  float t1 = aggpos[3*n+1] + pos[3*n+1]*d2;
  float t2 = aggpos[3*n+2] + pos[3*n+2]*d2;
  double acc = 0.0;
  for (int f = 0; f < 64; ++f){
    float h = t0*W1[f] + t1*W1[64+f] + t2*W1[128+f] + b1[f];
    h = leakyf(h);
    acc += (double)h * (double)p1[f];
  }
  double sc = tanh(acc * dscal[0]);
  score1[n] = (float)sc;
  u64 m = mono64(sc);
  key1[n] = (m & ~0x1FFFFull) | (u64)(131071 - n);
  atomicAdd(&hist1[(int)(m >> 48)], 1);
}

// ---------------- top-k selection (2-level histogram) ----------------
__global__ void k_scan1(const int* hist, int* meta){
  __shared__ int part[1024];
  int t = threadIdx.x;
  int s = 0;
  for (int b = t*64; b < t*64+64; ++b) s += hist[b];
  part[t] = s; __syncthreads();
  if (t == 0){
    int cum = 0;
    for (int c = 1023; c >= 0; --c){
      if (cum + part[c] >= KP1){
        int cc = cum;
        for (int b = c*64+63; b >= c*64; --b){
          int h = hist[b];
          if (cc + h >= KP1){ meta[1] = b; meta[2] = cc; meta[3] = KP1 - cc; return; }
          cc += h;
        }
      }
      cum += part[c];
    }
    meta[1] = 0; meta[2] = 0; meta[3] = KP1;
  }
}

__global__ void k_hist2(const u64* key1, const int* meta, int* hist2){
  int n = blockIdx.x*256 + threadIdx.x;
  if (n >= NNODES) return;
  u64 k = key1[n];
  if ((int)(k >> 48) == meta[1]) atomicAdd(&hist2[(int)((k >> 32) & 0xFFFF)], 1);
}

__global__ void k_scan2(const int* hist, int* meta){
  __shared__ int part[1024];
  int t = threadIdx.x;
  int s = 0;
  for (int b = t*64; b < t*64+64; ++b) s += hist[b];
  part[t] = s; __syncthreads();
  if (t == 0){
    int kt = meta[3];
    int cum = 0;
    int B2 = 0;
    for (int c = 1023; c >= 0; --c){
      if (cum + part[c] >= kt){
        int cc = cum;
        for (int b = c*64+63; b >= c*64; --b){
          int h = hist[b];
          if (cc + h >= kt){ B2 = b; goto done; }
          cc += h;
        }
      }
      cum += part[c];
    }
    done:
    meta[4] = B2;
    meta[5] = (int)(((u32)meta[1] << 16) | (u32)B2);
  }
}

__global__ void k_collect(const u64* key1, const int* meta, int* cand, int* cnt){
  int n = blockIdx.x*256 + threadIdx.x;
  if (n >= NNODES) return;
  u32 hi = (u32)(key1[n] >> 32);
  if (hi >= (u32)meta[5]){
    int p = atomicAdd(&cnt[0], 1);
    if (p < CAP_CAND) cand[p] = n;
  }
}

template<int SZ>
__device__ void bitonic_asc(u64* s){
  for (int k = 2; k <= SZ; k <<= 1){
    for (int j = k >> 1; j > 0; j >>= 1){
      for (int i = threadIdx.x; i < SZ; i += blockDim.x){
        int ixj = i ^ j;
        if (ixj > i){
          u64 a = s[i], c = s[ixj];
          bool asc = ((i & k) == 0);
          if (asc ? (a > c) : (a < c)){ s[i] = c; s[ixj] = a; }
        }
      }
      __syncthreads();
    }
  }
}

__global__ __launch_bounds__(1024) void k_sortsel(const u64* key1, const int* cand, const int* cnt,
                                                  const float* score1, int* perm1, float* sc1p, int* mapping){
  __shared__ u64 skey[CAP_CAND];
  int t = threadIdx.x;
  int C = cnt[0]; if (C > CAP_CAND) C = CAP_CAND;
  for (int i = t; i < CAP_CAND; i += 1024) skey[i] = (i < C) ? key1[cand[i]] : 0ull;
  __syncthreads();
  bitonic_asc<CAP_CAND>(skey);
  for (int r = t; r < KP1; r += 1024){
    u64 k = skey[CAP_CAND-1-r];
    int n = 131071 - (int)(k & 0x1FFFFull);
    perm1[r] = n;
    mapping[n] = r;
    sc1p[r] = score1[n];
  }
}

// x1p[r] = leaky(gcn1_row(perm1[r])) * score
__global__ void k_xnew1(const int* perm1, const float* pos, const float* aggpos, const float* dinv1,
                        const float* W1, const float* b1, const float* sc1p, float* x1p){
  int r = blockIdx.x, f = threadIdx.x;
  int n = perm1[r];
  float di = dinv1[n], d2 = di*di;
  float t0 = aggpos[3*n+0] + pos[3*n+0]*d2;
  float t1 = aggpos[3*n+1] + pos[3*n+1]*d2;
  float t2 = aggpos[3*n+2] + pos[3*n+2]*d2;
  float h = t0*W1[f] + t1*W1[64+f] + t2*W1[128+f] + b1[f];
  x1p[r*64+f] = leakyf(h) * sc1p[r];
}

// ---------------- pooled graph ----------------
__global__ void k_compact(const int* eb, const int* meta, const int* mapping,
                          int* src2, int* dst2, int* cnt, int* deg2){
  int e = blockIdx.x*256 + threadIdx.x;
  if (e >= NEDGES) return;
  int s, d; get_edge(eb, meta[0], e, s, d);
  int s2 = mapping[s], d2 = mapping[d];
  if (s2 >= 0 && d2 >= 0){
    int q = atomicAdd(&cnt[1], 1);
    src2[q] = s2; dst2[q] = d2;
    atomicAdd(&deg2[d2], 1);
  }
}

__global__ void k_dinv2(const int* deg2, float* dinv2){
  int n = blockIdx.x*256 + threadIdx.x;
  if (n >= KP1) return;
  dinv2[n] = (float)(1.0 / sqrt((double)deg2[n] + 1.0));
}

__global__ void k_agg64(const int* src2, const int* dst2, const int* cnt,
                        const float* dinv2, const float* x1p, float* agg64){
  int E = cnt[1];
  for (int e = blockIdx.x*blockDim.x + threadIdx.x; e < E; e += gridDim.x*blockDim.x){
    int s = src2[e], d = dst2[e];
    float nrm = dinv2[s]*dinv2[d];
    for (int f = 0; f < 64; ++f) atomicAdd(&agg64[d*64+f], x1p[s*64+f]*nrm);
  }
}

__global__ void k_x2(const float* agg64, const float* x1p, const float* dinv2,
                     const float* W2, const float* b2, float* x2){
  __shared__ float xin[64];
  int n = blockIdx.x, t = threadIdx.x;
  if (t < 64){
    float di = dinv2[n];
    xin[t] = agg64[n*64+t] + x1p[n*64+t]*di*di;
  }
  __syncthreads();
  float acc = 0.0f;
  for (int c = 0; c < 64; ++c) acc += xin[c]*W2[c*128+t];
  x2[n*128+t] = leakyf(acc + b2[t]);
}

__global__ void k_agg128(const int* src2, const int* dst2, const int* cnt,
                         const float* dinv2, const float* x2, float* agg128){
  int E = cnt[1];
  for (int e = blockIdx.x*blockDim.x + threadIdx.x; e < E; e += gridDim.x*blockDim.x){
    int s = src2[e], d = dst2[e];
    float nrm = dinv2[s]*dinv2[d];
    for (int f = 0; f < 128; ++f) atomicAdd(&agg128[d*128+f], x2[s*128+f]*nrm);
  }
}

__global__ void k_x3(const float* agg128, const float* x2, const float* dinv2,
                     const float* W3, const float* b3, float* x3){
  __shared__ float xin[128];
  int n = blockIdx.x, t = threadIdx.x;
  if (t < 128){
    float di = dinv2[n];
    xin[t] = agg128[n*128+t] + x2[n*128+t]*di*di;
  }
  __syncthreads();
  float acc = 0.0f;
  for (int c = 0; c < 128; ++c) acc += xin[c]*W3[c*256+t];
  x3[n*256+t] = leakyf(acc + b3[t]);
}

// ---------------- pool 2 ----------------
__global__ void k_score2(const float* x3, const float* p2, const double* dscal,
                         float* score2, u64* key2){
  int n = blockIdx.x*256 + threadIdx.x;
  if (n >= KP1) return;
  const float* row = x3 + (size_t)n*256;
  double acc = 0.0;
  for (int f = 0; f < 256; ++f) acc += (double)row[f] * (double)p2[f];
  double sc = tanh(acc * dscal[1]);
  score2[n] = (float)sc;
  key2[n] = (mono64(sc) & ~0x1FFFFull) | (u64)(131071 - n);
}

__global__ __launch_bounds__(1024) void k_sort2(const u64* key2, const float* score2,
                                                int* perm2, float* sc2){
  __shared__ u64 skey[KP1];
  int t = threadIdx.x;
  for (int i = t; i < KP1; i += 1024) skey[i] = key2[i];
  __syncthreads();
  bitonic_asc<KP1>(skey);
  for (int r = t; r < KP2; r += 1024){
    u64 k = skey[KP1-1-r];
    int n = 131071 - (int)(k & 0x1FFFFull);
    perm2[r] = n;
    sc2[r] = score2[n];
  }
}

// xflat[f*256+n] = x3[perm2[n]][f] * sc2[n]   (x.T.reshape(-1))
__global__ void k_xflat(const float* x3, const int* perm2, const float* sc2, float* xflat){
  int f = blockIdx.x, n = threadIdx.x;
  xflat[f*256+n] = x3[(size_t)perm2[n]*256 + f] * sc2[n];
}

// ---------------- final FC: y = xflat @ fcW + fcb ----------------
__global__ void k_fc(const float* xflat, const float* fcW, float* yacc){
  __shared__ float xs[128];
  int b = blockIdx.x, t = threadIdx.x;
  if (t < 128) xs[t] = xflat[b*128+t];
  __syncthreads();
  const float* Wp = fcW + (size_t)b*128*512 + t;
  float acc = 0.0f;
  #pragma unroll 8
  for (int i = 0; i < 128; ++i) acc += xs[i]*Wp[(size_t)i*512];
  atomicAdd(&yacc[t], acc);
}

__global__ void k_out(const float* yacc, const float* fcb, float* out){
  int t = threadIdx.x;
  out[t] = yacc[t] + fcb[t];
}

// ---------------- host ----------------
extern "C" void kernel_launch(void* const* d_in, const int* in_sizes, int n_in,
                              void* d_out, int out_size, void* d_ws, size_t ws_size,
                              hipStream_t stream){
  const float* pos = (const float*)d_in[0];
  const int*   eb  = (const int*)d_in[1];
  const float* W1  = (const float*)d_in[2];
  const float* b1  = (const float*)d_in[3];
  const float* W2  = (const float*)d_in[4];
  const float* b2  = (const float*)d_in[5];
  const float* W3  = (const float*)d_in[6];
  const float* b3  = (const float*)d_in[7];
  const float* p1  = (const float*)d_in[8];
  const float* p2  = (const float*)d_in[9];
  const float* fcW = (const float*)d_in[10];
  const float* fcb = (const float*)d_in[11];
  float* out = (float*)d_out;

  char* w = (char*)d_ws;
  size_t off = 0;
  auto alloc = [&](size_t bytes)->char*{
    char* p = w + off; off = (off + bytes + 255) & ~(size_t)255; return p;
  };
  // zero-init region (contiguous, one memset)
  int*   deg1   = (int*)  alloc((size_t)NNODES*4);
  float* aggpos = (float*)alloc((size_t)NNODES*3*4);
  int*   hist1  = (int*)  alloc(65536*4);
  int*   hist2  = (int*)  alloc(65536*4);
  int*   deg2   = (int*)  alloc(KP1*4);
  float* agg64  = (float*)alloc((size_t)KP1*64*4);
  float* agg128 = (float*)alloc((size_t)KP1*128*4);
  float* yacc   = (float*)alloc(512*4);
  int*   cnt    = (int*)  alloc(64*4);
  size_t zero_bytes = off;
  // mapping: init to -1
  int*   mapping= (int*)  alloc((size_t)NNODES*4);
  // uninitialized scratch
  int*    meta  = (int*)  alloc(64*4);
  double* dscal = (double*)alloc(8*8);
  float* dinv1  = (float*)alloc((size_t)NNODES*4);
  float* score1 = (float*)alloc((size_t)NNODES*4);
  u64*   key1   = (u64*)  alloc((size_t)NNODES*8);
  int*   cand   = (int*)  alloc(CAP_CAND*4);
  int*   perm1  = (int*)  alloc(KP1*4);
  float* sc1p   = (float*)alloc(KP1*4);
  float* x1p    = (float*)alloc((size_t)KP1*64*4);
  float* dinv2  = (float*)alloc(KP1*4);
  int*   src2   = (int*)  alloc((size_t)NEDGES*4);
  int*   dst2   = (int*)  alloc((size_t)NEDGES*4);
  float* x2     = (float*)alloc((size_t)KP1*128*4);
  float* x3     = (float*)alloc((size_t)KP1*256*4);
  float* score2 = (float*)alloc(KP1*4);
  u64*   key2   = (u64*)  alloc(KP1*8);
  int*   perm2  = (int*)  alloc(KP2*4);
  float* sc2    = (float*)alloc(KP2*4);
  float* xflat  = (float*)alloc(65536*4);
  if (off > ws_size) return;

  hipMemsetAsync(d_ws, 0, zero_bytes, stream);
  hipMemsetAsync(mapping, 0xFF, (size_t)NNODES*4, stream);

  k_meta<<<1,256,0,stream>>>(eb, p1, p2, meta, dscal);
  k_deg1<<<(NEDGES+255)/256,256,0,stream>>>(eb, meta, deg1);
  k_dinv1<<<(NNODES+255)/256,256,0,stream>>>(deg1, dinv1);
  k_aggpos<<<(NEDGES+255)/256,256,0,stream>>>(eb, meta, pos, dinv1, aggpos);
  k_score1<<<(NNODES+255)/256,256,0,stream>>>(pos, aggpos, dinv1, W1, b1, p1, dscal, score1, key1, hist1);
  k_scan1<<<1,1024,0,stream>>>(hist1, meta);
  k_hist2<<<(NNODES+255)/256,256,0,stream>>>(key1, meta, hist2);
  k_scan2<<<1,1024,0,stream>>>(hist2, meta);
  k_collect<<<(NNODES+255)/256,256,0,stream>>>(key1, meta, cand, cnt);
  k_sortsel<<<1,1024,0,stream>>>(key1, cand, cnt, score1, perm1, sc1p, mapping);
  k_xnew1<<<KP1,64,0,stream>>>(perm1, pos, aggpos, dinv1, W1, b1, sc1p, x1p);
  k_compact<<<(NEDGES+255)/256,256,0,stream>>>(eb, meta, mapping, src2, dst2, cnt, deg2);
  k_dinv2<<<(KP1+255)/256,256,0,stream>>>(deg2, dinv2);
  k_agg64<<<64,256,0,stream>>>(src2, dst2, cnt, dinv2, x1p, agg64);
  k_x2<<<KP1,128,0,stream>>>(agg64, x1p, dinv2, W2, b2, x2);
  k_agg128<<<64,256,0,stream>>>(src2, dst2, cnt, dinv2, x2, agg128);
  k_x3<<<KP1,256,0,stream>>>(agg128, x2, dinv2, W3, b3, x3);
  k_score2<<<(KP1+255)/256,256,0,stream>>>(x3, p2, dscal, score2, key2);
  k_sort2<<<1,1024,0,stream>>>(key2, score2, perm2, sc2);
  k_xflat<<<256,256,0,stream>>>(x3, perm2, sc2, xflat);
  k_fc<<<512,512,0,stream>>>(xflat, fcW, yacc);
  k_out<<<1,512,0,stream>>>(yacc, fcb, out);
}

// Round 2
// 662.725 us; speedup vs baseline: 1.4267x; 1.4267x over previous
//
#include <hip/hip_runtime.h>
#include <cstdint>
#include <cstddef>

#define NNODES 100000
#define NEDGES 1200000
#define KP1 4096
#define KP2 256
#define CAP_CAND 8192
#define CAP2 48
#define NBLK_SCAN 98   // ceil(100000/1024)

typedef unsigned long long u64;
typedef unsigned int u32;

__device__ __forceinline__ float leakyf(float v){ return v >= 0.0f ? v : 0.01f*v; }

__device__ __forceinline__ u64 mono64(double d){
  u64 b = (u64)__double_as_longlong(d);
  return (b & 0x8000000000000000ull) ? ~b : (b | 0x8000000000000000ull);
}

// edge fetch supporting int32 or int64 storage (flag=1 -> int64)
__device__ __forceinline__ void get_edge(const int* eb, int flag, int e, int& s, int& d){
  if (flag){ s = eb[2*e]; d = eb[2*(NEDGES+e)]; }
  else     { s = eb[e];   d = eb[NEDGES+e]; }
}

// ---------------- setup: p-norms + edge dtype detect ----------------
__global__ void k_meta(const int* eb, const float* p1, const float* p2, int* meta, double* dscal){
  __shared__ double red[256];
  int t = threadIdx.x;
  double s1 = 0.0;
  if (t < 64){ double v = (double)p1[t]; s1 = v*v; }
  red[t] = s1; __syncthreads();
  for (int w = 128; w > 0; w >>= 1){ if (t < w) red[t] += red[t+w]; __syncthreads(); }
  if (t == 0) dscal[0] = 1.0 / sqrt(red[0]);
  __syncthreads();
  double v2 = (double)p2[t];
  red[t] = v2*v2; __syncthreads();
  for (int w = 128; w > 0; w >>= 1){ if (t < w) red[t] += red[t+w]; __syncthreads(); }
  if (t == 0){
    dscal[1] = 1.0 / sqrt(red[0]);
    int is64 = 1;
    for (int i = 1; i <= 127; i += 2) if (eb[i] != 0){ is64 = 0; break; }
    meta[0] = is64;
  }
}

// ---------------- CSR build ----------------
__global__ void k_deg(const int* eb, const int* meta, int* deg1){
  int e = blockIdx.x*256 + threadIdx.x;
  if (e >= NEDGES) return;
  int s, d; get_edge(eb, meta[0], e, s, d);
  (void)s;
  atomicAdd(&deg1[d], 1);
}

__global__ __launch_bounds__(1024) void k_scanA(const int* deg, int* tmpscan, int* parts){
  __shared__ int sm[1024];
  int t = threadIdx.x, idx = blockIdx.x*1024 + t;
  int v = (idx < NNODES) ? deg[idx] : 0;
  sm[t] = v; __syncthreads();
  for (int o = 1; o < 1024; o <<= 1){
    int x = (t >= o) ? sm[t-o] : 0; __syncthreads();
    sm[t] += x; __syncthreads();
  }
  if (idx < NNODES) tmpscan[idx] = sm[t];
  if (t == 1023) parts[blockIdx.x] = sm[1023];
}

__global__ void k_scanB(int* parts){
  if (threadIdx.x == 0){
    int run = 0;
    for (int i = 0; i < NBLK_SCAN; ++i){ int v = parts[i]; parts[i] = run; run += v; }
  }
}

__global__ void k_scanC(const int* tmpscan, const int* deg, const int* parts, int* offs, int* cursor){
  int idx = blockIdx.x*256 + threadIdx.x;
  if (idx >= NNODES) return;
  int off = tmpscan[idx] - deg[idx] + parts[idx >> 10];
  offs[idx] = off;
  cursor[idx] = off;
}

__global__ void k_scatter(const int* eb, const int* meta, int* cursor, int* csr){
  int e = blockIdx.x*256 + threadIdx.x;
  if (e >= NEDGES) return;
  int s, d; get_edge(eb, meta[0], e, s, d);
  int slot = atomicAdd(&cursor[d], 1);
  csr[slot] = s;
}

__global__ void k_dinv1(const int* deg1, float* dinv1){
  int n = blockIdx.x*256 + threadIdx.x;
  if (n >= NNODES) return;
  dinv1[n] = (float)(1.0 / sqrt((double)deg1[n] + 1.0));
}

// ---------------- GCN1 gather + score (fused) ----------------
__global__ void k_score1(const int* offs, const int* deg1, const int* csr,
                         const float* pos, const float* dinv1,
                         const float* W1, const float* b1, const float* p1,
                         const double* dscal, float* aggsave, float* score1,
                         u64* key1, int* hist1){
  int n = blockIdx.x*256 + threadIdx.x;
  if (n >= NNODES) return;
  float di = dinv1[n];
  int base = offs[n], c = deg1[n];
  float t0 = 0.f, t1 = 0.f, t2 = 0.f;
  for (int j = 0; j < c; ++j){
    int s = csr[base+j];
    float ds = dinv1[s];
    t0 += ds*pos[3*s+0]; t1 += ds*pos[3*s+1]; t2 += ds*pos[3*s+2];
  }
  float d2 = di*di;
  t0 = t0*di + pos[3*n+0]*d2;
  t1 = t1*di + pos[3*n+1]*d2;
  t2 = t2*di + pos[3*n+2]*d2;
  aggsave[3*n+0] = t0; aggsave[3*n+1] = t1; aggsave[3*n+2] = t2;
  double acc = 0.0;
  for (int f = 0; f < 64; ++f){
    float h = t0*W1[f] + t1*W1[64+f] + t2*W1[128+f] + b1[f];
    h = leakyf(h);
    acc += (double)h * (double)p1[f];
  }
  double sc = tanh(acc * dscal[0]);
  score1[n] = (float)sc;
  u64 m = mono64(sc);
  key1[n] = (m & ~0x1FFFFull) | (u64)(131071 - n);
  atomicAdd(&hist1[(int)(m >> 48)], 1);
}

// ---------------- top-k selection (2-level histogram) ----------------
__global__ void k_scan1(const int* hist, int* meta){
  __shared__ int part[1024];
  int t = threadIdx.x;
  int s = 0;
  for (int b = t*64; b < t*64+64; ++b) s += hist[b];
  part[t] = s; __syncthreads();
  if (t == 0){
    int cum = 0;
    for (int c = 1023; c >= 0; --c){
      if (cum + part[c] >= KP1){
        int cc = cum;
        for (int b = c*64+63; b >= c*64; --b){
          int h = hist[b];
          if (cc + h >= KP1){ meta[1] = b; meta[2] = cc; meta[3] = KP1 - cc; return; }
          cc += h;
        }
      }
      cum += part[c];
    }
    meta[1] = 0; meta[2] = 0; meta[3] = KP1;
  }
}

__global__ void k_hist2(const u64* key1, const int* meta, int* hist2){
  int n = blockIdx.x*256 + threadIdx.x;
  if (n >= NNODES) return;
  u64 k = key1[n];
  if ((int)(k >> 48) == meta[1]) atomicAdd(&hist2[(int)((k >> 32) & 0xFFFF)], 1);
}

__global__ void k_scan2(const int* hist, int* meta){
  __shared__ int part[1024];
  int t = threadIdx.x;
  int s = 0;
  for (int b = t*64; b < t*64+64; ++b) s += hist[b];
  part[t] = s; __syncthreads();
  if (t == 0){
    int kt = meta[3];
    int cum = 0;
    int B2 = 0;
    for (int c = 1023; c >= 0; --c){
      if (cum + part[c] >= kt){
        int cc = cum;
        for (int b = c*64+63; b >= c*64; --b){
          int h = hist[b];
          if (cc + h >= kt){ B2 = b; goto done; }
          cc += h;
        }
      }
      cum += part[c];
    }
    done:
    meta[4] = B2;
    meta[5] = (int)(((u32)meta[1] << 16) | (u32)B2);
  }
}

__global__ void k_collect(const u64* key1, const int* meta, int* cand, int* cnt){
  int n = blockIdx.x*256 + threadIdx.x;
  if (n >= NNODES) return;
  u32 hi = (u32)(key1[n] >> 32);
  if (hi >= (u32)meta[5]){
    int p = atomicAdd(&cnt[0], 1);
    if (p < CAP_CAND) cand[p] = n;
  }
}

template<int SZ>
__device__ void bitonic_asc(u64* s){
  for (int k = 2; k <= SZ; k <<= 1){
    for (int j = k >> 1; j > 0; j >>= 1){
      for (int i = threadIdx.x; i < SZ; i += blockDim.x){
        int ixj = i ^ j;
        if (ixj > i){
          u64 a = s[i], c = s[ixj];
          bool asc = ((i & k) == 0);
          if (asc ? (a > c) : (a < c)){ s[i] = c; s[ixj] = a; }
        }
      }
      __syncthreads();
    }
  }
}

__global__ __launch_bounds__(1024) void k_sortsel(const u64* key1, const int* cand, const int* cnt,
                                                  const float* score1, int* perm1, float* sc1p, int* mapping){
  __shared__ u64 skey[CAP_CAND];
  int t = threadIdx.x;
  int C = cnt[0]; if (C > CAP_CAND) C = CAP_CAND;
  for (int i = t; i < CAP_CAND; i += 1024) skey[i] = (i < C) ? key1[cand[i]] : 0ull;
  __syncthreads();
  bitonic_asc<CAP_CAND>(skey);
  for (int r = t; r < KP1; r += 1024){
    u64 k = skey[CAP_CAND-1-r];
    int n = 131071 - (int)(k & 0x1FFFFull);
    perm1[r] = n;
    mapping[n] = r;
    sc1p[r] = score1[n];
  }
}

// x1p[r] = leaky(gcn1_row(perm1[r])) * score
__global__ void k_xnew1(const int* perm1, const float* aggsave,
                        const float* W1, const float* b1, const float* sc1p, float* x1p){
  int r = blockIdx.x, f = threadIdx.x;
  int n = perm1[r];
  float t0 = aggsave[3*n+0], t1 = aggsave[3*n+1], t2 = aggsave[3*n+2];
  float h = t0*W1[f] + t1*W1[64+f] + t2*W1[128+f] + b1[f];
  x1p[r*64+f] = leakyf(h) * sc1p[r];
}

// ---------------- pooled CSR via kept-node walk ----------------
__global__ void k_compact(const int* perm1, const int* offs, const int* deg1, const int* csr,
                          const int* mapping, int* csr2, int* deg2, float* dinv2){
  int r = blockIdx.x*256 + threadIdx.x;
  if (r >= KP1) return;
  int n = perm1[r];
  int base = offs[n], c = deg1[n];
  int k = 0;
  for (int j = 0; j < c; ++j){
    int m = mapping[csr[base+j]];
    if (m >= 0 && k < CAP2){ csr2[r*CAP2+k] = m; ++k; }
  }
  deg2[r] = k;
  dinv2[r] = (float)(1.0 / sqrt((double)k + 1.0));
}

// ---------------- GCN2 fused gather+matmul ----------------
__global__ __launch_bounds__(128) void k_x2(const int* csr2, const int* deg2, const float* dinv2,
                                            const float* x1p, const float* W2, const float* b2, float* x2){
  __shared__ float xin[64];
  int r = blockIdx.x, t = threadIdx.x;
  float dr = dinv2[r];
  if (t < 64){
    float a = 0.f;
    int c = deg2[r];
    for (int j = 0; j < c; ++j){
      int s = csr2[r*CAP2+j];
      a += x1p[s*64+t]*dinv2[s];
    }
    xin[t] = a*dr + x1p[r*64+t]*dr*dr;
  }
  __syncthreads();
  float acc = 0.f;
  for (int c = 0; c < 64; ++c) acc += xin[c]*W2[c*128+t];
  x2[r*128+t] = leakyf(acc + b2[t]);
}

// ---------------- GCN3 fused gather+matmul ----------------
__global__ __launch_bounds__(256) void k_x3(const int* csr2, const int* deg2, const float* dinv2,
                                            const float* x2, const float* W3, const float* b3, float* x3){
  __shared__ float xin[128];
  int r = blockIdx.x, t = threadIdx.x;
  float dr = dinv2[r];
  if (t < 128){
    float a = 0.f;
    int c = deg2[r];
    for (int j = 0; j < c; ++j){
      int s = csr2[r*CAP2+j];
      a += x2[s*128+t]*dinv2[s];
    }
    xin[t] = a*dr + x2[r*128+t]*dr*dr;
  }
  __syncthreads();
  float acc = 0.f;
  for (int c = 0; c < 128; ++c) acc += xin[c]*W3[c*256+t];
  x3[r*256+t] = leakyf(acc + b3[t]);
}

// ---------------- pool 2 ----------------
__global__ __launch_bounds__(256) void k_score2(const float* x3, const float* p2, const double* dscal,
                                                float* score2, u64* key2){
  __shared__ double red[256];
  int n = blockIdx.x, t = threadIdx.x;
  red[t] = (double)x3[n*256+t] * (double)p2[t];
  __syncthreads();
  for (int w = 128; w > 0; w >>= 1){ if (t < w) red[t] += red[t+w]; __syncthreads(); }
  if (t == 0){
    double sc = tanh(red[0] * dscal[1]);
    score2[n] = (float)sc;
    key2[n] = (mono64(sc) & ~0x1FFFFull) | (u64)(131071 - n);
  }
}

__global__ __launch_bounds__(1024) void k_sort2(const u64* key2, const float* score2,
                                                int* perm2, float* sc2){
  __shared__ u64 skey[KP1];
  int t = threadIdx.x;
  for (int i = t; i < KP1; i += 1024) skey[i] = key2[i];
  __syncthreads();
  bitonic_asc<KP1>(skey);
  for (int r = t; r < KP2; r += 1024){
    u64 k = skey[KP1-1-r];
    int n = 131071 - (int)(k & 0x1FFFFull);
    perm2[r] = n;
    sc2[r] = score2[n];
  }
}

// xflat[f*256+n] = x3[perm2[n]][f] * sc2[n]   (x.T.reshape(-1))
__global__ void k_xflat(const float* x3, const int* perm2, const float* sc2, float* xflat){
  int f = blockIdx.x, n = threadIdx.x;
  xflat[f*256+n] = x3[(size_t)perm2[n]*256 + f] * sc2[n];
}

// ---------------- final FC: partials then reduce ----------------
__global__ __launch_bounds__(512) void k_fc(const float* xflat, const float* fcW, float* partial){
  __shared__ float xs[128];
  int b = blockIdx.x, t = threadIdx.x;
  if (t < 128) xs[t] = xflat[b*128+t];
  __syncthreads();
  const float* Wp = fcW + (size_t)b*128*512 + t;
  float acc = 0.f;
  #pragma unroll 8
  for (int i = 0; i < 128; ++i) acc += xs[i]*Wp[(size_t)i*512];
  partial[b*512+t] = acc;
}

__global__ __launch_bounds__(128) void k_out(const float* partial, const float* fcb, float* out){
  __shared__ float red[128];
  int o = blockIdx.x, t = threadIdx.x;
  float a = 0.f;
  for (int b = t; b < 512; b += 128) a += partial[(size_t)b*512+o];
  red[t] = a; __syncthreads();
  for (int w = 64; w > 0; w >>= 1){ if (t < w) red[t] += red[t+w]; __syncthreads(); }
  if (t == 0) out[o] = red[0] + fcb[o];
}

// ---------------- host ----------------
extern "C" void kernel_launch(void* const* d_in, const int* in_sizes, int n_in,
                              void* d_out, int out_size, void* d_ws, size_t ws_size,
                              hipStream_t stream){
  const float* pos = (const float*)d_in[0];
  const int*   eb  = (const int*)d_in[1];
  const float* W1  = (const float*)d_in[2];
  const float* b1  = (const float*)d_in[3];
  const float* W2  = (const float*)d_in[4];
  const float* b2  = (const float*)d_in[5];
  const float* W3  = (const float*)d_in[6];
  const float* b3  = (const float*)d_in[7];
  const float* p1  = (const float*)d_in[8];
  const float* p2  = (const float*)d_in[9];
  const float* fcW = (const float*)d_in[10];
  const float* fcb = (const float*)d_in[11];
  float* out = (float*)d_out;

  char* w = (char*)d_ws;
  size_t off = 0;
  auto alloc = [&](size_t bytes)->char*{
    char* p = w + off; off = (off + bytes + 255) & ~(size_t)255; return p;
  };
  // zero-init region (contiguous, one memset)
  int*   deg1   = (int*)  alloc((size_t)NNODES*4);
  int*   hist1  = (int*)  alloc(65536*4);
  int*   hist2  = (int*)  alloc(65536*4);
  int*   cnt    = (int*)  alloc(64*4);
  size_t zero_bytes = off;
  // mapping: init to -1
  int*   mapping= (int*)  alloc((size_t)NNODES*4);
  // uninitialized scratch
  int*    meta  = (int*)  alloc(64*4);
  double* dscal = (double*)alloc(8*8);
  int*   tmpscan= (int*)  alloc((size_t)NNODES*4);
  int*   parts  = (int*)  alloc(NBLK_SCAN*4);
  int*   offs   = (int*)  alloc((size_t)NNODES*4);
  int*   cursor = (int*)  alloc((size_t)NNODES*4);
  int*   csr    = (int*)  alloc((size_t)NEDGES*4);
  float* dinv1  = (float*)alloc((size_t)NNODES*4);
  float* aggsave= (float*)alloc((size_t)NNODES*3*4);
  float* score1 = (float*)alloc((size_t)NNODES*4);
  u64*   key1   = (u64*)  alloc((size_t)NNODES*8);
  int*   cand   = (int*)  alloc(CAP_CAND*4);
  int*   perm1  = (int*)  alloc(KP1*4);
  float* sc1p   = (float*)alloc(KP1*4);
  float* x1p    = (float*)alloc((size_t)KP1*64*4);
  int*   csr2   = (int*)  alloc((size_t)KP1*CAP2*4);
  int*   deg2   = (int*)  alloc(KP1*4);
  float* dinv2  = (float*)alloc(KP1*4);
  float* x2     = (float*)alloc((size_t)KP1*128*4);
  float* x3     = (float*)alloc((size_t)KP1*256*4);
  float* score2 = (float*)alloc(KP1*4);
  u64*   key2   = (u64*)  alloc(KP1*8);
  int*   perm2  = (int*)  alloc(KP2*4);
  float* sc2    = (float*)alloc(KP2*4);
  float* xflat  = (float*)alloc(65536*4);
  float* partial= (float*)alloc((size_t)512*512*4);
  if (off > ws_size) return;

  hipMemsetAsync(d_ws, 0, zero_bytes, stream);
  hipMemsetAsync(mapping, 0xFF, (size_t)NNODES*4, stream);

  k_meta<<<1,256,0,stream>>>(eb, p1, p2, meta, dscal);
  k_deg<<<(NEDGES+255)/256,256,0,stream>>>(eb, meta, deg1);
  k_scanA<<<NBLK_SCAN,1024,0,stream>>>(deg1, tmpscan, parts);
  k_scanB<<<1,64,0,stream>>>(parts);
  k_scanC<<<(NNODES+255)/256,256,0,stream>>>(tmpscan, deg1, parts, offs, cursor);
  k_scatter<<<(NEDGES+255)/256,256,0,stream>>>(eb, meta, cursor, csr);
  k_dinv1<<<(NNODES+255)/256,256,0,stream>>>(deg1, dinv1);
  k_score1<<<(NNODES+255)/256,256,0,stream>>>(offs, deg1, csr, pos, dinv1, W1, b1, p1, dscal,
                                              aggsave, score1, key1, hist1);
  k_scan1<<<1,1024,0,stream>>>(hist1, meta);
  k_hist2<<<(NNODES+255)/256,256,0,stream>>>(key1, meta, hist2);
  k_scan2<<<1,1024,0,stream>>>(hist2, meta);
  k_collect<<<(NNODES+255)/256,256,0,stream>>>(key1, meta, cand, cnt);
  k_sortsel<<<1,1024,0,stream>>>(key1, cand, cnt, score1, perm1, sc1p, mapping);
  k_xnew1<<<KP1,64,0,stream>>>(perm1, aggsave, W1, b1, sc1p, x1p);
  k_compact<<<(KP1+255)/256,256,0,stream>>>(perm1, offs, deg1, csr, mapping, csr2, deg2, dinv2);
  k_x2<<<KP1,128,0,stream>>>(csr2, deg2, dinv2, x1p, W2, b2, x2);
  k_x3<<<KP1,256,0,stream>>>(csr2, deg2, dinv2, x2, W3, b3, x3);
  k_score2<<<KP1,256,0,stream>>>(x3, p2, dscal, score2, key2);
  k_sort2<<<1,1024,0,stream>>>(key2, score2, perm2, sc2);
  k_xflat<<<256,256,0,stream>>>(x3, perm2, sc2, xflat);
  k_fc<<<512,512,0,stream>>>(xflat, fcW, partial);
  k_out<<<512,128,0,stream>>>(partial, fcb, out);
}

// Round 3
// 579.112 us; speedup vs baseline: 1.6326x; 1.1444x over previous
//
#include <hip/hip_runtime.h>
#include <cstdint>
#include <cstddef>

#define NNODES 100000
#define NEDGES 1200000
#define KP1 4096
#define KP2 256
#define CAP_CAND 8192
#define CAP2 48
#define RTILE 2048
#define NBLK_SCAN 98   // ceil(100000/1024)

typedef unsigned long long u64;
typedef unsigned int u32;

__device__ __forceinline__ float leakyf(float v){ return v >= 0.0f ? v : 0.01f*v; }
__device__ __forceinline__ double leakyd(double v){ return v >= 0.0 ? v : 0.01*v; }

__device__ __forceinline__ u64 mono64(double d){
  u64 b = (u64)__double_as_longlong(d);
  return (b & 0x8000000000000000ull) ? ~b : (b | 0x8000000000000000ull);
}

// edge fetch supporting int32 or int64 storage (flag=1 -> int64)
__device__ __forceinline__ void get_edge(const int* eb, int flag, int e, int& s, int& d){
  if (flag){ s = eb[2*e]; d = eb[2*(NEDGES+e)]; }
  else     { s = eb[e];   d = eb[NEDGES+e]; }
}

// ---------------- setup: p-norms + edge dtype detect ----------------
__global__ void k_meta(const int* eb, const float* p1, const float* p2, int* meta, double* dscal){
  __shared__ double red[256];
  int t = threadIdx.x;
  double s1 = 0.0;
  if (t < 64){ double v = (double)p1[t]; s1 = v*v; }
  red[t] = s1; __syncthreads();
  for (int w = 128; w > 0; w >>= 1){ if (t < w) red[t] += red[t+w]; __syncthreads(); }
  if (t == 0) dscal[0] = 1.0 / sqrt(red[0]);
  __syncthreads();
  double v2 = (double)p2[t];
  red[t] = v2*v2; __syncthreads();
  for (int w = 128; w > 0; w >>= 1){ if (t < w) red[t] += red[t+w]; __syncthreads(); }
  if (t == 0){
    dscal[1] = 1.0 / sqrt(red[0]);
    int is64 = 1;
    for (int i = 1; i <= 127; i += 2) if (eb[i] != 0){ is64 = 0; break; }
    meta[0] = is64;
  }
}

// ---------------- CSR build ----------------
__global__ void k_deg(const int* eb, const int* meta, int* deg1){
  int e = blockIdx.x*256 + threadIdx.x;
  if (e >= NEDGES) return;
  int s, d; get_edge(eb, meta[0], e, s, d);
  (void)s;
  atomicAdd(&deg1[d], 1);
}

__global__ __launch_bounds__(1024) void k_scanA(const int* deg, int* tmpscan, int* parts){
  __shared__ int sm[1024];
  int t = threadIdx.x, idx = blockIdx.x*1024 + t;
  int v = (idx < NNODES) ? deg[idx] : 0;
  sm[t] = v; __syncthreads();
  for (int o = 1; o < 1024; o <<= 1){
    int x = (t >= o) ? sm[t-o] : 0; __syncthreads();
    sm[t] += x; __syncthreads();
  }
  if (idx < NNODES) tmpscan[idx] = sm[t];
  if (t == 1023) parts[blockIdx.x] = sm[1023];
}

__global__ void k_scanB(int* parts){
  if (threadIdx.x == 0){
    int run = 0;
    for (int i = 0; i < NBLK_SCAN; ++i){ int v = parts[i]; parts[i] = run; run += v; }
  }
}

__global__ void k_scanC(const int* tmpscan, const int* deg, const int* parts,
                        int* offs, int* cursor, float* dinv1){
  int idx = blockIdx.x*256 + threadIdx.x;
  if (idx >= NNODES) return;
  int off = tmpscan[idx] - deg[idx] + parts[idx >> 10];
  offs[idx] = off;
  cursor[idx] = off;
  dinv1[idx] = (float)(1.0 / sqrt((double)deg[idx] + 1.0));
}

__global__ void k_scatter(const int* eb, const int* meta, int* cursor, int* csr){
  int e = blockIdx.x*256 + threadIdx.x;
  if (e >= NEDGES) return;
  int s, d; get_edge(eb, meta[0], e, s, d);
  int slot = atomicAdd(&cursor[d], 1);
  csr[slot] = s;
}

// ---------------- GCN1 gather + score (fused, f64 accumulate) ----------------
__global__ void k_score1(const int* offs, const int* deg1, const int* csr,
                         const float* pos, const float* dinv1,
                         const float* W1, const float* b1, const float* p1,
                         const double* dscal, double* aggsave, float* score1,
                         u64* key1, int* hist1){
  int n = blockIdx.x*256 + threadIdx.x;
  if (n >= NNODES) return;
  double di = (double)dinv1[n];
  int base = offs[n], c = deg1[n];
  double t0 = 0.0, t1 = 0.0, t2 = 0.0;
  for (int j = 0; j < c; ++j){
    int s = csr[base+j];
    double ds = (double)dinv1[s];
    t0 += ds*(double)pos[3*s+0]; t1 += ds*(double)pos[3*s+1]; t2 += ds*(double)pos[3*s+2];
  }
  double d2 = di*di;
  t0 = t0*di + (double)pos[3*n+0]*d2;
  t1 = t1*di + (double)pos[3*n+1]*d2;
  t2 = t2*di + (double)pos[3*n+2]*d2;
  aggsave[3*n+0] = t0; aggsave[3*n+1] = t1; aggsave[3*n+2] = t2;
  double acc = 0.0;
  for (int f = 0; f < 64; ++f){
    double h = t0*(double)W1[f] + t1*(double)W1[64+f] + t2*(double)W1[128+f] + (double)b1[f];
    h = leakyd(h);
    acc += h * (double)p1[f];
  }
  double sc = tanh(acc * dscal[0]);
  score1[n] = (float)sc;
  u64 m = mono64(sc);
  key1[n] = (m & ~0x1FFFFull) | (u64)(131071 - n);
  atomicAdd(&hist1[(int)(m >> 48)], 1);
}

// ---------------- top-k selection (2-level histogram -> candidates) ----------------
__global__ void k_scan1(const int* hist, int* meta){
  __shared__ int part[1024];
  int t = threadIdx.x;
  int s = 0;
  for (int b = t*64; b < t*64+64; ++b) s += hist[b];
  part[t] = s; __syncthreads();
  if (t == 0){
    int cum = 0;
    for (int c = 1023; c >= 0; --c){
      if (cum + part[c] >= KP1){
        int cc = cum;
        for (int b = c*64+63; b >= c*64; --b){
          int h = hist[b];
          if (cc + h >= KP1){ meta[1] = b; meta[2] = cc; meta[3] = KP1 - cc; return; }
          cc += h;
        }
      }
      cum += part[c];
    }
    meta[1] = 0; meta[2] = 0; meta[3] = KP1;
  }
}

__global__ void k_hist2(const u64* key1, const int* meta, int* hist2){
  int n = blockIdx.x*256 + threadIdx.x;
  if (n >= NNODES) return;
  u64 k = key1[n];
  if ((int)(k >> 48) == meta[1]) atomicAdd(&hist2[(int)((k >> 32) & 0xFFFF)], 1);
}

__global__ void k_scan2(const int* hist, int* meta){
  __shared__ int part[1024];
  int t = threadIdx.x;
  int s = 0;
  for (int b = t*64; b < t*64+64; ++b) s += hist[b];
  part[t] = s; __syncthreads();
  if (t == 0){
    int kt = meta[3];
    int cum = 0;
    int B2 = 0;
    for (int c = 1023; c >= 0; --c){
      if (cum + part[c] >= kt){
        int cc = cum;
        for (int b = c*64+63; b >= c*64; --b){
          int h = hist[b];
          if (cc + h >= kt){ B2 = b; goto done; }
          cc += h;
        }
      }
      cum += part[c];
    }
    done:
    meta[4] = B2;
    meta[5] = (int)(((u32)meta[1] << 16) | (u32)B2);
  }
}

__global__ void k_collect(const u64* key1, const int* meta, int* cand, int* cnt){
  int n = blockIdx.x*256 + threadIdx.x;
  if (n >= NNODES) return;
  u32 hi = (u32)(key1[n] >> 32);
  if (hi >= (u32)meta[5]){
    int p = atomicAdd(&cnt[0], 1);
    if (p < CAP_CAND) cand[p] = n;
  }
}

// ---------------- rank-select (replaces bitonic sort) ----------------
__global__ __launch_bounds__(256) void k_rank1(const u64* key1, const int* cand, const int* cnt,
                                               const float* score1, int* perm1, float* sc1p, int* mapping){
  __shared__ u64 tile[RTILE];
  int C = cnt[0]; if (C > CAP_CAND) C = CAP_CAND;
  if (blockIdx.x*256 >= C) return;
  int idx = blockIdx.x*256 + threadIdx.x;
  bool live = idx < C;
  u64 mykey = 0; int node = 0;
  if (live){ node = cand[idx]; mykey = key1[node]; }
  int rank = 0;
  int ntiles = (C + RTILE - 1)/RTILE;
  for (int tb = 0; tb < ntiles; ++tb){
    int base = tb*RTILE;
    int len = C - base; if (len > RTILE) len = RTILE;
    for (int i = threadIdx.x; i < RTILE; i += 256)
      tile[i] = (base+i < C) ? key1[cand[base+i]] : 0ull;
    __syncthreads();
    if (live){
      for (int i = 0; i < len; ++i) rank += (tile[i] > mykey) ? 1 : 0;
    }
    __syncthreads();
  }
  if (live && rank < KP1){
    perm1[rank] = node;
    mapping[node] = rank;
    sc1p[rank] = score1[node];
  }
}

// x1p[r] = leaky(gcn1_row(perm1[r])) * score
__global__ void k_xnew1(const int* perm1, const double* aggsave,
                        const float* W1, const float* b1, const float* sc1p, float* x1p){
  int r = blockIdx.x, f = threadIdx.x;
  int n = perm1[r];
  double t0 = aggsave[3*n+0], t1 = aggsave[3*n+1], t2 = aggsave[3*n+2];
  double h = t0*(double)W1[f] + t1*(double)W1[64+f] + t2*(double)W1[128+f] + (double)b1[f];
  x1p[r*64+f] = (float)(leakyd(h) * (double)sc1p[r]);
}

// ---------------- pooled CSR via kept-node walk ----------------
__global__ void k_compact(const int* perm1, const int* offs, const int* deg1, const int* csr,
                          const int* mapping, int* csr2, int* deg2, float* dinv2){
  int r = blockIdx.x*256 + threadIdx.x;
  if (r >= KP1) return;
  int n = perm1[r];
  int base = offs[n], c = deg1[n];
  int k = 0;
  for (int j = 0; j < c; ++j){
    int m = mapping[csr[base+j]];
    if (m >= 0 && k < CAP2){ csr2[r*CAP2+k] = m; ++k; }
  }
  deg2[r] = k;
  dinv2[r] = (float)(1.0 / sqrt((double)k + 1.0));
}

// ---------------- GCN2 fused gather+matmul (f64 accumulate) ----------------
__global__ __launch_bounds__(128) void k_x2(const int* csr2, const int* deg2, const float* dinv2,
                                            const float* x1p, const float* W2, const float* b2, float* x2){
  __shared__ double xin[64];
  int r = blockIdx.x, t = threadIdx.x;
  double dr = (double)dinv2[r];
  if (t < 64){
    double a = 0.0;
    int c = deg2[r];
    for (int j = 0; j < c; ++j){
      int s = csr2[r*CAP2+j];
      a += (double)x1p[s*64+t]*(double)dinv2[s];
    }
    xin[t] = a*dr + (double)x1p[r*64+t]*dr*dr;
  }
  __syncthreads();
  double acc = 0.0;
  for (int c = 0; c < 64; ++c) acc += xin[c]*(double)W2[c*128+t];
  x2[r*128+t] = (float)leakyd(acc + (double)b2[t]);
}

// ---------------- GCN3 fused gather+matmul (f64 accumulate) ----------------
__global__ __launch_bounds__(256) void k_x3(const int* csr2, const int* deg2, const float* dinv2,
                                            const float* x2, const float* W3, const float* b3, float* x3){
  __shared__ double xin[128];
  int r = blockIdx.x, t = threadIdx.x;
  double dr = (double)dinv2[r];
  if (t < 128){
    double a = 0.0;
    int c = deg2[r];
    for (int j = 0; j < c; ++j){
      int s = csr2[r*CAP2+j];
      a += (double)x2[s*128+t]*(double)dinv2[s];
    }
    xin[t] = a*dr + (double)x2[r*128+t]*dr*dr;
  }
  __syncthreads();
  double acc = 0.0;
  for (int c = 0; c < 128; ++c) acc += xin[c]*(double)W3[c*256+t];
  x3[r*256+t] = (float)leakyd(acc + (double)b3[t]);
}

// ---------------- pool 2 ----------------
__global__ __launch_bounds__(256) void k_score2(const float* x3, const float* p2, const double* dscal,
                                                float* score2, u64* key2){
  __shared__ double red[256];
  int n = blockIdx.x, t = threadIdx.x;
  red[t] = (double)x3[n*256+t] * (double)p2[t];
  __syncthreads();
  for (int w = 128; w > 0; w >>= 1){ if (t < w) red[t] += red[t+w]; __syncthreads(); }
  if (t == 0){
    double sc = tanh(red[0] * dscal[1]);
    score2[n] = (float)sc;
    key2[n] = (mono64(sc) & ~0x1FFFFull) | (u64)(131071 - n);
  }
}

__global__ __launch_bounds__(256) void k_rank2(const u64* key2, const float* score2,
                                               int* perm2, float* sc2){
  __shared__ u64 tile[RTILE];
  int idx = blockIdx.x*256 + threadIdx.x;
  u64 mykey = key2[idx];
  int rank = 0;
  for (int tb = 0; tb < KP1/RTILE; ++tb){
    for (int i = threadIdx.x; i < RTILE; i += 256) tile[i] = key2[tb*RTILE+i];
    __syncthreads();
    for (int i = 0; i < RTILE; ++i) rank += (tile[i] > mykey) ? 1 : 0;
    __syncthreads();
  }
  if (rank < KP2){
    perm2[rank] = idx;
    sc2[rank] = score2[idx];
  }
}

// xflat[f*256+n] = x3[perm2[n]][f] * sc2[n]   (x.T.reshape(-1))
__global__ void k_xflat(const float* x3, const int* perm2, const float* sc2, float* xflat){
  int f = blockIdx.x, n = threadIdx.x;
  xflat[f*256+n] = x3[(size_t)perm2[n]*256 + f] * sc2[n];
}

// ---------------- final FC: partials (f64) then reduce ----------------
__global__ __launch_bounds__(512) void k_fc(const float* xflat, const float* fcW, double* partial){
  __shared__ float xs[128];
  int b = blockIdx.x, t = threadIdx.x;
  if (t < 128) xs[t] = xflat[b*128+t];
  __syncthreads();
  const float* Wp = fcW + (size_t)b*128*512 + t;
  double acc = 0.0;
  #pragma unroll 8
  for (int i = 0; i < 128; ++i) acc += (double)xs[i]*(double)Wp[(size_t)i*512];
  partial[b*512+t] = acc;
}

__global__ __launch_bounds__(128) void k_out(const double* partial, const float* fcb, float* out){
  __shared__ double red[128];
  int o = blockIdx.x, t = threadIdx.x;
  double a = 0.0;
  for (int b = t; b < 512; b += 128) a += partial[(size_t)b*512+o];
  red[t] = a; __syncthreads();
  for (int w = 64; w > 0; w >>= 1){ if (t < w) red[t] += red[t+w]; __syncthreads(); }
  if (t == 0) out[o] = (float)(red[0] + (double)fcb[o]);
}

// ---------------- host ----------------
extern "C" void kernel_launch(void* const* d_in, const int* in_sizes, int n_in,
                              void* d_out, int out_size, void* d_ws, size_t ws_size,
                              hipStream_t stream){
  const float* pos = (const float*)d_in[0];
  const int*   eb  = (const int*)d_in[1];
  const float* W1  = (const float*)d_in[2];
  const float* b1  = (const float*)d_in[3];
  const float* W2  = (const float*)d_in[4];
  const float* b2  = (const float*)d_in[5];
  const float* W3  = (const float*)d_in[6];
  const float* b3  = (const float*)d_in[7];
  const float* p1  = (const float*)d_in[8];
  const float* p2  = (const float*)d_in[9];
  const float* fcW = (const float*)d_in[10];
  const float* fcb = (const float*)d_in[11];
  float* out = (float*)d_out;

  char* w = (char*)d_ws;
  size_t off = 0;
  auto alloc = [&](size_t bytes)->char*{
    char* p = w + off; off = (off + bytes + 255) & ~(size_t)255; return p;
  };
  // zero-init region (contiguous, one memset)
  int*   deg1   = (int*)  alloc((size_t)NNODES*4);
  int*   hist1  = (int*)  alloc(65536*4);
  int*   hist2  = (int*)  alloc(65536*4);
  int*   cnt    = (int*)  alloc(64*4);
  size_t zero_bytes = off;
  // mapping: init to -1
  int*   mapping= (int*)  alloc((size_t)NNODES*4);
  // uninitialized scratch
  int*    meta  = (int*)  alloc(64*4);
  double* dscal = (double*)alloc(8*8);
  int*   tmpscan= (int*)  alloc((size_t)NNODES*4);
  int*   parts  = (int*)  alloc(NBLK_SCAN*4);
  int*   offs   = (int*)  alloc((size_t)NNODES*4);
  int*   cursor = (int*)  alloc((size_t)NNODES*4);
  int*   csr    = (int*)  alloc((size_t)NEDGES*4);
  float* dinv1  = (float*)alloc((size_t)NNODES*4);
  double* aggsave=(double*)alloc((size_t)NNODES*3*8);
  float* score1 = (float*)alloc((size_t)NNODES*4);
  u64*   key1   = (u64*)  alloc((size_t)NNODES*8);
  int*   cand   = (int*)  alloc(CAP_CAND*4);
  int*   perm1  = (int*)  alloc(KP1*4);
  float* sc1p   = (float*)alloc(KP1*4);
  float* x1p    = (float*)alloc((size_t)KP1*64*4);
  int*   csr2   = (int*)  alloc((size_t)KP1*CAP2*4);
  int*   deg2   = (int*)  alloc(KP1*4);
  float* dinv2  = (float*)alloc(KP1*4);
  float* x2     = (float*)alloc((size_t)KP1*128*4);
  float* x3     = (float*)alloc((size_t)KP1*256*4);
  float* score2 = (float*)alloc(KP1*4);
  u64*   key2   = (u64*)  alloc(KP1*8);
  int*   perm2  = (int*)  alloc(KP2*4);
  float* sc2    = (float*)alloc(KP2*4);
  float* xflat  = (float*)alloc(65536*4);
  double* partial=(double*)alloc((size_t)512*512*8);
  if (off > ws_size) return;

  hipMemsetAsync(d_ws, 0, zero_bytes, stream);
  hipMemsetAsync(mapping, 0xFF, (size_t)NNODES*4, stream);

  k_meta<<<1,256,0,stream>>>(eb, p1, p2, meta, dscal);
  k_deg<<<(NEDGES+255)/256,256,0,stream>>>(eb, meta, deg1);
  k_scanA<<<NBLK_SCAN,1024,0,stream>>>(deg1, tmpscan, parts);
  k_scanB<<<1,64,0,stream>>>(parts);
  k_scanC<<<(NNODES+255)/256,256,0,stream>>>(tmpscan, deg1, parts, offs, cursor, dinv1);
  k_scatter<<<(NEDGES+255)/256,256,0,stream>>>(eb, meta, cursor, csr);
  k_score1<<<(NNODES+255)/256,256,0,stream>>>(offs, deg1, csr, pos, dinv1, W1, b1, p1, dscal,
                                              aggsave, score1, key1, hist1);
  k_scan1<<<1,1024,0,stream>>>(hist1, meta);
  k_hist2<<<(NNODES+255)/256,256,0,stream>>>(key1, meta, hist2);
  k_scan2<<<1,1024,0,stream>>>(hist2, meta);
  k_collect<<<(NNODES+255)/256,256,0,stream>>>(key1, meta, cand, cnt);
  k_rank1<<<CAP_CAND/256,256,0,stream>>>(key1, cand, cnt, score1, perm1, sc1p, mapping);
  k_xnew1<<<KP1,64,0,stream>>>(perm1, aggsave, W1, b1, sc1p, x1p);
  k_compact<<<(KP1+255)/256,256,0,stream>>>(perm1, offs, deg1, csr, mapping, csr2, deg2, dinv2);
  k_x2<<<KP1,128,0,stream>>>(csr2, deg2, dinv2, x1p, W2, b2, x2);
  k_x3<<<KP1,256,0,stream>>>(csr2, deg2, dinv2, x2, W3, b3, x3);
  k_score2<<<KP1,256,0,stream>>>(x3, p2, dscal, score2, key2);
  k_rank2<<<KP1/256,256,0,stream>>>(key2, score2, perm2, sc2);
  k_xflat<<<256,256,0,stream>>>(x3, perm2, sc2, xflat);
  k_fc<<<512,512,0,stream>>>(xflat, fcW, partial);
  k_out<<<512,128,0,stream>>>(partial, fcb, out);
}